// Round 9
// baseline (407.485 us; speedup 1.0000x reference)
//
#include <hip/hip_runtime.h>

// Problem constants
#define NQ     16384       // 4*16*16*16 query vectors
#define EDIM   256
#define NE     8192
#define LHW    4096        // 16*16*16
#define BETA   0.25f

// ws layout (bytes)
#define WS_WSQ    0            // f32[NE]             32768
#define WS_CNT    32768        // u32[NE]             32768
#define WS_LOSS   65536        // f32 (+pad)          256
#define WS_IDX    65792        // u32[NQ]             65536
#define WS_BEST   131328       // u64[NQ] (fallback)  131072
#define WS_BEST2  262400       // u64[8][NQ][2]       2097152
#define WS_APACK  2359552      // ushort[NQ*512]      16777216
#define WS_BPACK  19136768     // ushort[NE*512]      8388608
#define WS_NEED   27525376

typedef __attribute__((ext_vector_type(8))) short bf16x8;
typedef __attribute__((ext_vector_type(4))) float f32x4;

__device__ __forceinline__ unsigned f32_sortable(float f) {
    unsigned b = __float_as_uint(f);
    return (b & 0x80000000u) ? ~b : (b | 0x80000000u);
}
__device__ __forceinline__ unsigned short bf16_rn(float f) {
    unsigned u = __float_as_uint(f);
    return (unsigned short)((u + 0x7FFFu + ((u >> 16) & 1u)) >> 16);
}
__device__ __forceinline__ float bf16_tof(unsigned short h) {
    return __uint_as_float(((unsigned)h) << 16);
}

// K1: wsq[e] = sum_d w[e][d]^2 (f64 accumulate to minimize argmin tie flips).
__global__ __launch_bounds__(256) void wsq_kernel(const float* __restrict__ w,
                                                  float* __restrict__ wsq) {
    int wave = threadIdx.x >> 6, lane = threadIdx.x & 63;
    int row = blockIdx.x * 4 + wave;
    float4 v = *(const float4*)(w + (size_t)row * EDIM + lane * 4);
    double s = (double)v.x * v.x + (double)v.y * v.y +
               (double)v.z * v.z + (double)v.w * v.w;
    #pragma unroll
    for (int off = 32; off; off >>= 1) s += __shfl_xor(s, off, 64);
    if (lane == 0) wsq[row] = (float)s;
}

// pack_z: z fp32 [4][256][4096] -> Ap bf16 hi/lo ROW-MAJOR [n][512].
__global__ __launch_bounds__(256) void pack_z(const float* __restrict__ z,
                                              unsigned* __restrict__ Ap32) {
    __shared__ unsigned lds[64 * 257];
    int tid = threadIdx.x;
    int tn = tid & 63, tc = tid >> 6;
    int n0 = blockIdx.x * 64;
    int n = n0 + tn;
    int b = n >> 12, lhw = n & 4095;
    for (int cc = 0; cc < 64; ++cc) {
        int d = tc * 64 + cc;
        float v = z[((size_t)b * EDIM + d) * LHW + lhw];
        unsigned short hi = bf16_rn(v);
        unsigned short lo = bf16_rn(v - bf16_tof(hi));
        lds[tn * 257 + d] = (unsigned)hi | ((unsigned)lo << 16);
    }
    __syncthreads();
    for (int p = 0; p < 64; ++p) {
        int flat = p * 256 + tid;
        int row = flat >> 8, cl = flat & 255;
        Ap32[(size_t)(n0 + row) * 256 + cl] = lds[row * 257 + cl];
    }
}

// pack_w: codebook -> Bp bf16 hi/lo ROW-MAJOR [e][512].
__global__ __launch_bounds__(256) void pack_w(const float* __restrict__ w,
                                              unsigned* __restrict__ Bp32) {
    int tid = threadIdx.x;
    int e0 = blockIdx.x * 16;
    for (int r = 0; r < 16; ++r) {
        int e = e0 + r;
        float v = w[(size_t)e * EDIM + tid];
        unsigned short hi = bf16_rn(v);
        unsigned short lo = bf16_rn(v - bf16_tof(hi));
        Bp32[(size_t)e * 256 + tid] = (unsigned)hi | ((unsigned)lo << 16);
    }
}

// K2-MFMA v6: round-8 structure + DOUBLE-BUFFERED B staging with a single
// barrier per kcc. glds for chunk k+1 issues at the TOP of iteration k, so the
// end-of-iteration __syncthreads vmcnt(0) drain lands after ~400 cyc of
// ds_read+MFMA compute (beats the m97 barrier-drain problem within HIP).
// Buffer hazard clean: reads of buf[(k+1)&1] ended at the k-1 barrier.
// grid (64 e-splits, 128 nt); block 256 = 4 waves; wave tile 32n x 128e.
// A: direct global->VGPR, double-buffered regs. B: glds into 2x16KB swizzled LDS.
// Regs ~164 incl AGPR acc -> (256,2), 2 blocks/CU, no spill.
__global__ __launch_bounds__(256, 2) void dist_mfma(const unsigned short* __restrict__ Ap,
                                                    const unsigned short* __restrict__ Bp,
                                                    const float* __restrict__ wsq,
                                                    unsigned long long* __restrict__ s1) {
    __shared__ __align__(16) unsigned short lds_b[2][128 * 64];   // 2 x 16 KB, swizzled
    int tid = threadIdx.x, lane = tid & 63, w = tid >> 6;
    int x = blockIdx.x, nt = blockIdx.y;
    int quad = lane >> 4, col = lane & 15;
    int rsel = lane >> 3, seg = lane & 7;   // glds: 8 rows x 8 segs of 16B per call

    const unsigned short* arow = Ap + (size_t)(nt * 128 + w * 32 + col) * 512;
    const unsigned short* Bbase = Bp + (size_t)(x * 128) * 512;

    f32x4 acc[2][8];
    #pragma unroll
    for (int i = 0; i < 2; ++i)
        #pragma unroll
        for (int j = 0; j < 8; ++j) acc[i][j] = (f32x4){0.f, 0.f, 0.f, 0.f};

    bf16x8 af[2][2][2];   // [buf][i][h]

    // prologue: stage chunk 0 into buf 0, A chunk 0 into af[0]
    #pragma unroll
    for (int p = 0; p < 4; ++p) {
        int c = w * 4 + p;
        const unsigned short* gb =
            Bbase + (size_t)(c * 8 + rsel) * 512 + 0 + ((seg ^ (rsel & 7)) * 8);
        __builtin_amdgcn_global_load_lds(
            (const __attribute__((address_space(1))) void*)gb,
            (__attribute__((address_space(3))) void*)(&lds_b[0][c * 512]),
            16, 0, 0);
    }
    #pragma unroll
    for (int i = 0; i < 2; ++i)
        #pragma unroll
        for (int h = 0; h < 2; ++h)
            af[0][i][h] = *(const bf16x8*)(arow + i * 16 * 512 + h * 32 + quad * 8);
    __syncthreads();   // drain prologue staging

    #pragma unroll
    for (int kcc = 0; kcc < 8; ++kcc) {
        int cur = kcc & 1, nxt = cur ^ 1;
        // TOP: issue next chunk's staging so it overlaps this chunk's compute
        if (kcc < 7) {
            int k1 = (kcc + 1) * 64;
            #pragma unroll
            for (int p = 0; p < 4; ++p) {
                int c = w * 4 + p;
                const unsigned short* gb =
                    Bbase + (size_t)(c * 8 + rsel) * 512 + k1 + ((seg ^ (rsel & 7)) * 8);
                __builtin_amdgcn_global_load_lds(
                    (const __attribute__((address_space(1))) void*)gb,
                    (__attribute__((address_space(3))) void*)(&lds_b[nxt][c * 512]),
                    16, 0, 0);
            }
            #pragma unroll
            for (int i = 0; i < 2; ++i)
                #pragma unroll
                for (int h = 0; h < 2; ++h)
                    af[nxt][i][h] = *(const bf16x8*)(arow + i * 16 * 512 + k1 +
                                                     h * 32 + quad * 8);
        }
        // compute on current chunk
        #pragma unroll
        for (int h = 0; h < 2; ++h) {
            bf16x8 bf[8];
            #pragma unroll
            for (int j = 0; j < 8; ++j)
                bf[j] = *(const bf16x8*)(&lds_b[cur][(j * 16 + col) * 64 +
                                         (((h * 4 + quad) ^ (col & 7)) * 8)]);
            #pragma unroll
            for (int i = 0; i < 2; ++i)
                #pragma unroll
                for (int j = 0; j < 8; ++j)
                    acc[i][j] = __builtin_amdgcn_mfma_f32_16x16x32_bf16(
                        af[cur][i][h], bf[j], acc[i][j], 0, 0, 0);
        }
        __syncthreads();   // drains in-flight staging (overlapped) + buffer reuse fence
    }

    // epilogue: d = wsq[e] - 2*dot, top-2 over this block's 128 e
    unsigned long long m1[2][4], m2[2][4];
    #pragma unroll
    for (int i = 0; i < 2; ++i)
        #pragma unroll
        for (int r = 0; r < 4; ++r) { m1[i][r] = ~0ull; m2[i][r] = ~0ull; }
    int e_base = x * 128 + col;
    #pragma unroll
    for (int j = 0; j < 8; ++j) {
        int e = e_base + j * 16;
        float wq = wsq[e];
        #pragma unroll
        for (int i = 0; i < 2; ++i)
            #pragma unroll
            for (int r = 0; r < 4; ++r) {
                float d = fmaf(-2.0f, acc[i][j][r], wq);
                unsigned long long key =
                    ((unsigned long long)f32_sortable(d) << 32) | (unsigned)e;
                if (key < m1[i][r]) { m2[i][r] = m1[i][r]; m1[i][r] = key; }
                else if (key < m2[i][r]) m2[i][r] = key;
            }
    }
    // cross-lane top-2 merge within each 16-lane e-group, write per (q, slice)
    #pragma unroll
    for (int i = 0; i < 2; ++i)
        #pragma unroll
        for (int r = 0; r < 4; ++r) {
            unsigned long long a1 = m1[i][r], a2 = m2[i][r];
            #pragma unroll
            for (int off = 1; off < 16; off <<= 1) {
                unsigned long long b1 = __shfl_xor(a1, off, 64);
                unsigned long long b2 = __shfl_xor(a2, off, 64);
                unsigned long long lo1 = a1 < b1 ? a1 : b1;
                unsigned long long hi1 = a1 < b1 ? b1 : a1;
                unsigned long long lo2 = a2 < b2 ? a2 : b2;
                a1 = lo1;
                a2 = hi1 < lo2 ? hi1 : lo2;
            }
            if (col == 0) {
                int q = nt * 128 + w * 32 + i * 16 + quad * 4 + r;
                size_t o = (size_t)q * 128 + x * 2;
                s1[o] = a1; s1[o + 1] = a2;
            }
        }
}

// merge: [q][64 slices][2] u64 -> per-1024-e-group top-2 [8][NQ][2].
__global__ __launch_bounds__(256) void merge_kernel(const unsigned long long* __restrict__ s1,
                                                    unsigned long long* __restrict__ best2) {
    int q = blockIdx.x * 256 + threadIdx.x;
    const unsigned long long* p = s1 + (size_t)q * 128;
    #pragma unroll
    for (int g = 0; g < 8; ++g) {
        unsigned long long m1 = ~0ull, m2 = ~0ull;
        #pragma unroll
        for (int i = 0; i < 16; ++i) {
            unsigned long long k = p[g * 16 + i];
            if (k < m1) { m2 = m1; m1 = k; }
            else if (k < m2) m2 = k;
        }
        size_t o = ((size_t)g * NQ + q) * 2;
        best2[o] = m1; best2[o + 1] = m2;
    }
}

// Refinement: exact fp32 distance for the 16 candidates per query; true argmin
// with first-index tiebreak. One wave per query.
__global__ __launch_bounds__(256) void refine_kernel(const float* __restrict__ z,
                                                     const float* __restrict__ w,
                                                     const float* __restrict__ wsq,
                                                     const unsigned long long* __restrict__ best2,
                                                     unsigned* __restrict__ idxarr) {
    int tid = threadIdx.x, lane = tid & 63, wv = tid >> 6;
    int q = blockIdx.x * 4 + wv;
    int b = q >> 12, lhw = q & 4095;
    float zv[4];
    #pragma unroll
    for (int t = 0; t < 4; ++t)
        zv[t] = z[((size_t)b * EDIM + lane * 4 + t) * LHW + lhw];
    unsigned long long bestk = ~0ull;
    for (int c = 0; c < 16; ++c) {
        unsigned long long k = best2[((size_t)(c >> 1) * NQ + q) * 2 + (c & 1)];
        unsigned e = (unsigned)(k & 0xFFFFFFFFull) & (NE - 1);
        float4 wv4 = *(const float4*)(w + (size_t)e * EDIM + lane * 4);
        float p = zv[0] * wv4.x + zv[1] * wv4.y + zv[2] * wv4.z + zv[3] * wv4.w;
        #pragma unroll
        for (int off = 32; off; off >>= 1) p += __shfl_xor(p, off, 64);
        float d = wsq[e] - 2.0f * p;
        unsigned long long key = ((unsigned long long)f32_sortable(d) << 32) | e;
        if (key < bestk) bestk = key;
    }
    if (lane == 0) idxarr[q] = (unsigned)(bestk & 0xFFFFFFFFull);
}

// ---------- fallback fp32 path (used when ws_size < WS_NEED) ----------
__global__ __launch_bounds__(256, 2) void dist_fp32(const float* __restrict__ z,
                                                    const float* __restrict__ w,
                                                    const float* __restrict__ wsq,
                                                    unsigned long long* __restrict__ best) {
    __shared__ float lds_a[32 * 128];
    __shared__ float lds_b[32 * 132];
    int tid = threadIdx.x;
    int tx = tid & 15, ty = tid >> 4;
    int n0 = blockIdx.y * 128;
    int bb_ = n0 >> 12, lhw0 = n0 & 4095;
    const float* zb = z + (size_t)bb_ * (EDIM * LHW) + lhw0;
    int ebase = blockIdx.x * 2048;
    unsigned long long runmin[8];
    #pragma unroll
    for (int i = 0; i < 8; ++i) runmin[i] = ~0ull;
    float acc[64];
    for (int et = 0; et < 16; ++et) {
        int e0 = ebase + et * 128;
        #pragma unroll
        for (int i = 0; i < 64; ++i) acc[i] = 0.f;
        for (int kc = 0; kc < 8; ++kc) {
            int k0 = kc * 32;
            #pragma unroll
            for (int p = 0; p < 4; ++p) {
                int f = p * 256 + tid;
                int kk = f >> 5, nn4 = f & 31;
                float4 v = *(const float4*)(zb + (size_t)(k0 + kk) * LHW + nn4 * 4);
                *((float4*)(lds_a + kk * 128 + nn4 * 4)) = v;
            }
            #pragma unroll
            for (int p = 0; p < 4; ++p) {
                int f = p * 256 + tid;
                int ee = f >> 3, kk4 = f & 7;
                float4 v = *(const float4*)(w + (size_t)(e0 + ee) * EDIM + k0 + kk4 * 4);
                lds_b[(kk4 * 4 + 0) * 132 + ee] = v.x;
                lds_b[(kk4 * 4 + 1) * 132 + ee] = v.y;
                lds_b[(kk4 * 4 + 2) * 132 + ee] = v.z;
                lds_b[(kk4 * 4 + 3) * 132 + ee] = v.w;
            }
            __syncthreads();
            #pragma unroll
            for (int k = 0; k < 32; ++k) {
                float a[8], bv[8];
                *(float4*)(a)      = *(float4*)(lds_a + k * 128 + ty * 8);
                *(float4*)(a + 4)  = *(float4*)(lds_a + k * 128 + ty * 8 + 4);
                *(float4*)(bv)     = *(float4*)(lds_b + k * 132 + tx * 8);
                *(float4*)(bv + 4) = *(float4*)(lds_b + k * 132 + tx * 8 + 4);
                #pragma unroll
                for (int i = 0; i < 8; ++i)
                    #pragma unroll
                    for (int j = 0; j < 8; ++j)
                        acc[i * 8 + j] = fmaf(a[i], bv[j], acc[i * 8 + j]);
            }
            __syncthreads();
        }
        #pragma unroll
        for (int i = 0; i < 8; ++i) {
            unsigned long long m = runmin[i];
            #pragma unroll
            for (int j = 0; j < 8; ++j) {
                int e = e0 + tx * 8 + j;
                float d = wsq[e] - 2.0f * acc[i * 8 + j];
                unsigned long long key =
                    ((unsigned long long)f32_sortable(d) << 32) | (unsigned)e;
                m = (m < key) ? m : key;
            }
            runmin[i] = m;
        }
    }
    #pragma unroll
    for (int i = 0; i < 8; ++i) {
        unsigned long long kk = runmin[i];
        #pragma unroll
        for (int off = 8; off >= 1; off >>= 1) {
            unsigned long long o = __shfl_xor(kk, off, 16);
            kk = (kk < o) ? kk : o;
        }
        if (tx == 0) atomicMin(&best[n0 + ty * 8 + i], kk);
    }
}

__global__ __launch_bounds__(256) void extract_idx(const unsigned long long* __restrict__ best,
                                                   unsigned* __restrict__ idxarr) {
    int n = blockIdx.x * 256 + threadIdx.x;
    idxarr[n] = (unsigned)(best[n] & 0xFFFFFFFFull) & (NE - 1);
}

// K3: gather codebook rows, transpose-write z_q_st, loss partials, histogram, idx out.
__global__ __launch_bounds__(256) void gather_kernel(const float* __restrict__ z,
                                                     const float* __restrict__ w,
                                                     const unsigned* __restrict__ idxarr,
                                                     unsigned* __restrict__ counts,
                                                     float* __restrict__ loss,
                                                     float* __restrict__ out,
                                                     float* __restrict__ out_idx) {
    __shared__ int idx_s[64];
    __shared__ float wl[64 * 257];
    int tid = threadIdx.x;
    int n0 = blockIdx.x * 64;
    if (tid < 64) {
        int idx = (int)(idxarr[n0 + tid] & (NE - 1));
        idx_s[tid] = idx;
        out_idx[n0 + tid] = (float)idx;
        atomicAdd(&counts[idx], 1u);
    }
    __syncthreads();
    for (int i = 0; i < 64; ++i)
        wl[i * 257 + tid] = w[(size_t)idx_s[i] * EDIM + tid];
    __syncthreads();
    int tn = tid & 63, tc = tid >> 6;
    int bb_ = n0 >> 12, lhw0 = n0 & 4095;
    size_t zb = (size_t)bb_ * (EDIM * LHW) + lhw0 + tn;
    float accl = 0.f;
    for (int cc = 0; cc < 64; ++cc) {
        int c = tc * 64 + cc;
        float wv = wl[tn * 257 + c];
        size_t a = zb + (size_t)c * LHW;
        float zv = z[a];
        float diff = wv - zv;            // z_q - zc
        out[a] = zv + diff;              // replicate zc + (z_q - zc) rounding
        accl += diff * diff;
    }
    #pragma unroll
    for (int off = 32; off; off >>= 1) accl += __shfl_xor(accl, off, 64);
    if ((tid & 63) == 0) atomicAdd(loss, accl);
}

// K4: scalars
__global__ __launch_bounds__(256) void finalize_kernel(const unsigned* __restrict__ counts,
                                                       const float* __restrict__ loss,
                                                       float* __restrict__ out_scalars) {
    __shared__ float ss[4];
    __shared__ int uu[4];
    int tid = threadIdx.x;
    float s = 0.f;
    int uniq = 0;
    for (int i = tid; i < NE; i += 256) {
        unsigned c = counts[i];
        if (c > 0) {
            float p = (float)c * (1.0f / (float)NQ);
            s += p * logf(p + 1e-10f);
            uniq++;
        }
    }
    #pragma unroll
    for (int off = 32; off; off >>= 1) {
        s += __shfl_xor(s, off, 64);
        uniq += __shfl_xor(uniq, off, 64);
    }
    int wave = tid >> 6;
    if ((tid & 63) == 0) { ss[wave] = s; uu[wave] = uniq; }
    __syncthreads();
    if (tid == 0) {
        float st = ss[0] + ss[1] + ss[2] + ss[3];
        int ut = uu[0] + uu[1] + uu[2] + uu[3];
        out_scalars[0] = BETA * loss[0] * (1.0f / (float)(NQ * EDIM));  // loss
        out_scalars[1] = expf(-st);                                     // perplexity
        out_scalars[2] = (float)ut;                                     // unique
    }
}

extern "C" void kernel_launch(void* const* d_in, const int* in_sizes, int n_in,
                              void* d_out, int out_size, void* d_ws, size_t ws_size,
                              hipStream_t stream) {
    const float* z = (const float*)d_in[0];
    const float* w = (const float*)d_in[1];
    float* out = (float*)d_out;
    char* ws = (char*)d_ws;
    float* wsq = (float*)(ws + WS_WSQ);
    unsigned* counts = (unsigned*)(ws + WS_CNT);
    float* loss = (float*)(ws + WS_LOSS);
    unsigned* idxarr = (unsigned*)(ws + WS_IDX);
    unsigned long long* best = (unsigned long long*)(ws + WS_BEST);
    unsigned long long* best2 = (unsigned long long*)(ws + WS_BEST2);
    unsigned* Ap = (unsigned*)(ws + WS_APACK);
    unsigned* Bp = (unsigned*)(ws + WS_BPACK);

    int idx_off = out_size - NQ;
    int scal_off = idx_off - 3;
    float* out_idx = out + idx_off;
    float* out_scalars = out + scal_off;

    // z_q region of d_out doubles as the per-slice top-2 scratch (written by
    // dist_mfma, read by merge_kernel, then overwritten by gather_kernel).
    unsigned long long* s1 = (unsigned long long*)out;

    hipMemsetAsync(counts, 0, NE * sizeof(unsigned), stream);
    hipMemsetAsync(loss, 0, sizeof(float), stream);

    wsq_kernel<<<NE / 4, 256, 0, stream>>>(w, wsq);

    if (ws_size >= (size_t)WS_NEED) {
        pack_z<<<NQ / 64, 256, 0, stream>>>(z, Ap);
        pack_w<<<NE / 16, 256, 0, stream>>>(w, Bp);
        dist_mfma<<<dim3(64, 128), 256, 0, stream>>>((const unsigned short*)Ap,
                                                     (const unsigned short*)Bp, wsq, s1);
        merge_kernel<<<NQ / 256, 256, 0, stream>>>(s1, best2);
        refine_kernel<<<NQ / 4, 256, 0, stream>>>(z, w, wsq, best2, idxarr);
    } else {
        hipMemsetAsync(best, 0xFF, NQ * sizeof(unsigned long long), stream);
        dist_fp32<<<dim3(4, 128), 256, 0, stream>>>(z, w, wsq, best);
        extract_idx<<<NQ / 256, 256, 0, stream>>>(best, idxarr);
    }

    gather_kernel<<<NQ / 64, 256, 0, stream>>>(z, w, idxarr, counts, loss, out, out_idx);
    finalize_kernel<<<1, 256, 0, stream>>>(counts, loss, out_scalars);
}

// Round 10
// 342.405 us; speedup vs baseline: 1.1901x; 1.1901x over previous
//
#include <hip/hip_runtime.h>

// Problem constants
#define NQ     16384       // 4*16*16*16 query vectors
#define EDIM   256
#define NE     8192
#define LHW    4096        // 16*16*16
#define BETA   0.25f

// ws layout (bytes)
#define WS_WSQ    0            // f32[NE]             32768
#define WS_CNT    32768        // u32[NE]             32768
#define WS_LOSS   65536        // f32 (+pad)          256
#define WS_IDX    65792        // u32[NQ]             65536
#define WS_BEST   131328       // u64[NQ] (fallback)  131072
#define WS_BEST2  262400       // u64[8][NQ][2]       2097152
#define WS_APACK  2359552      // ushort[NQ*512]      16777216
#define WS_BPACK  19136768     // ushort[NE*512]      8388608
#define WS_NEED   27525376

typedef __attribute__((ext_vector_type(8))) short bf16x8;
typedef __attribute__((ext_vector_type(4))) float f32x4;

__device__ __forceinline__ unsigned f32_sortable(float f) {
    unsigned b = __float_as_uint(f);
    return b ^ ((unsigned)((int)b >> 31) | 0x80000000u);   // 3 VALU ops
}
__device__ __forceinline__ unsigned short bf16_rn(float f) {
    unsigned u = __float_as_uint(f);
    return (unsigned short)((u + 0x7FFFu + ((u >> 16) & 1u)) >> 16);
}
__device__ __forceinline__ float bf16_tof(unsigned short h) {
    return __uint_as_float(((unsigned)h) << 16);
}

// K1: wsq[e] = sum_d w[e][d]^2 (f64 accumulate to minimize argmin tie flips).
__global__ __launch_bounds__(256) void wsq_kernel(const float* __restrict__ w,
                                                  float* __restrict__ wsq) {
    int wave = threadIdx.x >> 6, lane = threadIdx.x & 63;
    int row = blockIdx.x * 4 + wave;
    float4 v = *(const float4*)(w + (size_t)row * EDIM + lane * 4);
    double s = (double)v.x * v.x + (double)v.y * v.y +
               (double)v.z * v.z + (double)v.w * v.w;
    #pragma unroll
    for (int off = 32; off; off >>= 1) s += __shfl_xor(s, off, 64);
    if (lane == 0) wsq[row] = (float)s;
}

// pack_z: z fp32 [4][256][4096] -> Ap bf16 hi/lo ROW-MAJOR [n][512].
__global__ __launch_bounds__(256) void pack_z(const float* __restrict__ z,
                                              unsigned* __restrict__ Ap32) {
    __shared__ unsigned lds[64 * 257];
    int tid = threadIdx.x;
    int tn = tid & 63, tc = tid >> 6;
    int n0 = blockIdx.x * 64;
    int n = n0 + tn;
    int b = n >> 12, lhw = n & 4095;
    for (int cc = 0; cc < 64; ++cc) {
        int d = tc * 64 + cc;
        float v = z[((size_t)b * EDIM + d) * LHW + lhw];
        unsigned short hi = bf16_rn(v);
        unsigned short lo = bf16_rn(v - bf16_tof(hi));
        lds[tn * 257 + d] = (unsigned)hi | ((unsigned)lo << 16);
    }
    __syncthreads();
    for (int p = 0; p < 64; ++p) {
        int flat = p * 256 + tid;
        int row = flat >> 8, cl = flat & 255;
        Ap32[(size_t)(n0 + row) * 256 + cl] = lds[row * 257 + cl];
    }
}

// pack_w: codebook -> Bp bf16 hi/lo ROW-MAJOR [e][512].
__global__ __launch_bounds__(256) void pack_w(const float* __restrict__ w,
                                              unsigned* __restrict__ Bp32) {
    int tid = threadIdx.x;
    int e0 = blockIdx.x * 16;
    for (int r = 0; r < 16; ++r) {
        int e = e0 + r;
        float v = w[(size_t)e * EDIM + tid];
        unsigned short hi = bf16_rn(v);
        unsigned short lo = bf16_rn(v - bf16_tof(hi));
        Bp32[(size_t)e * 256 + tid] = (unsigned)hi | ((unsigned)lo << 16);
    }
}

// K2-MFMA v7: round-8's verified K-loop (213 µs) + cheap u32 epilogue.
// grid (64 e-splits, 128 nt); block 256 = 4 waves; wave tile 32n x 128e.
// A: direct global->VGPR. B: glds-staged 16KB/chunk, XOR-swizzled LDS.
// Epilogue: per distance 8 VALU ops — k = (sortable(d) & ~127) | (j*16+col)
// (low 7 bits = e_local, exact in-slice first-index tiebreak), branchless
// top-2 via m2=min(m2,max(m1,k)); m1=min(m1,k). Round-9 lesson: no explicit
// double-buffer (compiler barrier scheduling defeats it; m99/m100 reproduced).
__global__ __launch_bounds__(256, 2) void dist_mfma(const unsigned short* __restrict__ Ap,
                                                    const unsigned short* __restrict__ Bp,
                                                    const float* __restrict__ wsq,
                                                    unsigned* __restrict__ s1) {
    __shared__ __align__(16) unsigned short lds_b[128 * 64];   // 16 KB, swizzled
    int tid = threadIdx.x, lane = tid & 63, w = tid >> 6;
    int x = blockIdx.x, nt = blockIdx.y;
    int quad = lane >> 4, col = lane & 15;
    int rsel = lane >> 3, seg = lane & 7;   // glds: 8 rows x 8 segs of 16B per call

    const unsigned short* arow = Ap + (size_t)(nt * 128 + w * 32 + col) * 512;
    const unsigned short* Bbase = Bp + (size_t)(x * 128) * 512;

    f32x4 acc[2][8];
    #pragma unroll
    for (int i = 0; i < 2; ++i)
        #pragma unroll
        for (int j = 0; j < 8; ++j) acc[i][j] = (f32x4){0.f, 0.f, 0.f, 0.f};

    for (int kcc = 0; kcc < 8; ++kcc) {
        int k0 = kcc * 64;
        // A frags for this 64k chunk: global -> VGPR (L2-resident tile)
        bf16x8 af[2][2];
        #pragma unroll
        for (int i = 0; i < 2; ++i)
            #pragma unroll
            for (int h = 0; h < 2; ++h)
                af[i][h] = *(const bf16x8*)(arow + i * 16 * 512 + k0 + h * 32 + quad * 8);
        __syncthreads();   // previous chunk's LDS readers done
        // stage B chunk: 16 calls of 1KB (4/wave), XOR-swizzled source so the
        // fragment ds_reads land 2-way bank-aliased. LDS row = 64 shorts.
        #pragma unroll
        for (int p = 0; p < 4; ++p) {
            int c = w * 4 + p;
            const unsigned short* gb =
                Bbase + (size_t)(c * 8 + rsel) * 512 + k0 + ((seg ^ (rsel & 7)) * 8);
            __builtin_amdgcn_global_load_lds(
                (const __attribute__((address_space(1))) void*)gb,
                (__attribute__((address_space(3))) void*)(lds_b + c * 512),
                16, 0, 0);
        }
        __syncthreads();   // drains vmcnt (glds + A loads)
        #pragma unroll
        for (int h = 0; h < 2; ++h) {
            bf16x8 bf[8];
            #pragma unroll
            for (int j = 0; j < 8; ++j)
                bf[j] = *(const bf16x8*)(lds_b + (j * 16 + col) * 64 +
                                         (((h * 4 + quad) ^ (col & 7)) * 8));
            #pragma unroll
            for (int i = 0; i < 2; ++i)
                #pragma unroll
                for (int j = 0; j < 8; ++j)
                    acc[i][j] = __builtin_amdgcn_mfma_f32_16x16x32_bf16(
                        af[i][h], bf[j], acc[i][j], 0, 0, 0);
        }
    }

    // epilogue: d = wsq[e] - 2*dot; u32 key = trunc-sortable(d) | e_local;
    // branchless top-2 per (i,r), then cross-lane merge over 16 e-lanes.
    unsigned m1[2][4], m2[2][4];
    #pragma unroll
    for (int i = 0; i < 2; ++i)
        #pragma unroll
        for (int r = 0; r < 4; ++r) { m1[i][r] = 0xFFFFFFFFu; m2[i][r] = 0xFFFFFFFFu; }
    #pragma unroll
    for (int j = 0; j < 8; ++j) {
        int e = x * 128 + j * 16 + col;
        unsigned jc = (unsigned)(j * 16 + col);   // e_local, 7 bits
        float wq = wsq[e];
        #pragma unroll
        for (int i = 0; i < 2; ++i)
            #pragma unroll
            for (int r = 0; r < 4; ++r) {
                float d = fmaf(-2.0f, acc[i][j][r], wq);
                unsigned k = (f32_sortable(d) & 0xFFFFFF80u) | jc;
                unsigned mx = (m1[i][r] > k) ? m1[i][r] : k;
                m1[i][r] = (m1[i][r] < k) ? m1[i][r] : k;
                m2[i][r] = (m2[i][r] < mx) ? m2[i][r] : mx;
            }
    }
    // cross-lane top-2 merge within each 16-lane e-group, write per (q, slice)
    #pragma unroll
    for (int i = 0; i < 2; ++i)
        #pragma unroll
        for (int r = 0; r < 4; ++r) {
            unsigned a1 = m1[i][r], a2 = m2[i][r];
            #pragma unroll
            for (int off = 1; off < 16; off <<= 1) {
                unsigned b1 = __shfl_xor(a1, off, 64);
                unsigned b2 = __shfl_xor(a2, off, 64);
                unsigned lo1 = a1 < b1 ? a1 : b1;
                unsigned hi1 = a1 < b1 ? b1 : a1;
                unsigned lo2 = a2 < b2 ? a2 : b2;
                a1 = lo1;
                a2 = hi1 < lo2 ? hi1 : lo2;
            }
            if (col == 0) {
                int q = nt * 128 + w * 32 + i * 16 + quad * 4 + r;
                size_t o = (size_t)q * 128 + x * 2;
                s1[o] = a1; s1[o + 1] = a2;
            }
        }
}

// merge: [q][64 slices][2] u32 -> per-1024-e-group top-2 [8][NQ][2] u64 keys
// key64 = (d_trunc << 13) | e_global  (refine extracts e via & (NE-1)).
__global__ __launch_bounds__(256) void merge_kernel(const unsigned* __restrict__ s1,
                                                    unsigned long long* __restrict__ best2) {
    int q = blockIdx.x * 256 + threadIdx.x;
    const unsigned* p = s1 + (size_t)q * 128;
    #pragma unroll
    for (int g = 0; g < 8; ++g) {
        unsigned long long m1 = ~0ull, m2 = ~0ull;
        #pragma unroll
        for (int s = 0; s < 8; ++s) {
            int x = g * 8 + s;
            #pragma unroll
            for (int t = 0; t < 2; ++t) {
                unsigned k = p[x * 2 + t];
                unsigned e = ((unsigned)x << 7) | (k & 127u);
                unsigned long long key =
                    ((unsigned long long)(k >> 7) << 13) | e;
                if (key < m1) { m2 = m1; m1 = key; }
                else if (key < m2) m2 = key;
            }
        }
        size_t o = ((size_t)g * NQ + q) * 2;
        best2[o] = m1; best2[o + 1] = m2;
    }
}

// Refinement: exact fp32 distance for the 16 candidates per query; true argmin
// with first-index tiebreak. One wave per query.
__global__ __launch_bounds__(256) void refine_kernel(const float* __restrict__ z,
                                                     const float* __restrict__ w,
                                                     const float* __restrict__ wsq,
                                                     const unsigned long long* __restrict__ best2,
                                                     unsigned* __restrict__ idxarr) {
    int tid = threadIdx.x, lane = tid & 63, wv = tid >> 6;
    int q = blockIdx.x * 4 + wv;
    int b = q >> 12, lhw = q & 4095;
    float zv[4];
    #pragma unroll
    for (int t = 0; t < 4; ++t)
        zv[t] = z[((size_t)b * EDIM + lane * 4 + t) * LHW + lhw];
    unsigned long long bestk = ~0ull;
    for (int c = 0; c < 16; ++c) {
        unsigned long long k = best2[((size_t)(c >> 1) * NQ + q) * 2 + (c & 1)];
        unsigned e = (unsigned)(k & 0xFFFFFFFFull) & (NE - 1);
        float4 wv4 = *(const float4*)(w + (size_t)e * EDIM + lane * 4);
        float p = zv[0] * wv4.x + zv[1] * wv4.y + zv[2] * wv4.z + zv[3] * wv4.w;
        #pragma unroll
        for (int off = 32; off; off >>= 1) p += __shfl_xor(p, off, 64);
        float d = wsq[e] - 2.0f * p;
        unsigned long long key = ((unsigned long long)f32_sortable(d) << 32) | e;
        if (key < bestk) bestk = key;
    }
    if (lane == 0) idxarr[q] = (unsigned)(bestk & 0xFFFFFFFFull);
}

// ---------- fallback fp32 path (used when ws_size < WS_NEED) ----------
__global__ __launch_bounds__(256, 2) void dist_fp32(const float* __restrict__ z,
                                                    const float* __restrict__ w,
                                                    const float* __restrict__ wsq,
                                                    unsigned long long* __restrict__ best) {
    __shared__ float lds_a[32 * 128];
    __shared__ float lds_b[32 * 132];
    int tid = threadIdx.x;
    int tx = tid & 15, ty = tid >> 4;
    int n0 = blockIdx.y * 128;
    int bb_ = n0 >> 12, lhw0 = n0 & 4095;
    const float* zb = z + (size_t)bb_ * (EDIM * LHW) + lhw0;
    int ebase = blockIdx.x * 2048;
    unsigned long long runmin[8];
    #pragma unroll
    for (int i = 0; i < 8; ++i) runmin[i] = ~0ull;
    float acc[64];
    for (int et = 0; et < 16; ++et) {
        int e0 = ebase + et * 128;
        #pragma unroll
        for (int i = 0; i < 64; ++i) acc[i] = 0.f;
        for (int kc = 0; kc < 8; ++kc) {
            int k0 = kc * 32;
            #pragma unroll
            for (int p = 0; p < 4; ++p) {
                int f = p * 256 + tid;
                int kk = f >> 5, nn4 = f & 31;
                float4 v = *(const float4*)(zb + (size_t)(k0 + kk) * LHW + nn4 * 4);
                *((float4*)(lds_a + kk * 128 + nn4 * 4)) = v;
            }
            #pragma unroll
            for (int p = 0; p < 4; ++p) {
                int f = p * 256 + tid;
                int ee = f >> 3, kk4 = f & 7;
                float4 v = *(const float4*)(w + (size_t)(e0 + ee) * EDIM + k0 + kk4 * 4);
                lds_b[(kk4 * 4 + 0) * 132 + ee] = v.x;
                lds_b[(kk4 * 4 + 1) * 132 + ee] = v.y;
                lds_b[(kk4 * 4 + 2) * 132 + ee] = v.z;
                lds_b[(kk4 * 4 + 3) * 132 + ee] = v.w;
            }
            __syncthreads();
            #pragma unroll
            for (int k = 0; k < 32; ++k) {
                float a[8], bv[8];
                *(float4*)(a)      = *(float4*)(lds_a + k * 128 + ty * 8);
                *(float4*)(a + 4)  = *(float4*)(lds_a + k * 128 + ty * 8 + 4);
                *(float4*)(bv)     = *(float4*)(lds_b + k * 132 + tx * 8);
                *(float4*)(bv + 4) = *(float4*)(lds_b + k * 132 + tx * 8 + 4);
                #pragma unroll
                for (int i = 0; i < 8; ++i)
                    #pragma unroll
                    for (int j = 0; j < 8; ++j)
                        acc[i * 8 + j] = fmaf(a[i], bv[j], acc[i * 8 + j]);
            }
            __syncthreads();
        }
        #pragma unroll
        for (int i = 0; i < 8; ++i) {
            unsigned long long m = runmin[i];
            #pragma unroll
            for (int j = 0; j < 8; ++j) {
                int e = e0 + tx * 8 + j;
                float d = wsq[e] - 2.0f * acc[i * 8 + j];
                unsigned long long key =
                    ((unsigned long long)f32_sortable(d) << 32) | (unsigned)e;
                m = (m < key) ? m : key;
            }
            runmin[i] = m;
        }
    }
    #pragma unroll
    for (int i = 0; i < 8; ++i) {
        unsigned long long kk = runmin[i];
        #pragma unroll
        for (int off = 8; off >= 1; off >>= 1) {
            unsigned long long o = __shfl_xor(kk, off, 16);
            kk = (kk < o) ? kk : o;
        }
        if (tx == 0) atomicMin(&best[n0 + ty * 8 + i], kk);
    }
}

__global__ __launch_bounds__(256) void extract_idx(const unsigned long long* __restrict__ best,
                                                   unsigned* __restrict__ idxarr) {
    int n = blockIdx.x * 256 + threadIdx.x;
    idxarr[n] = (unsigned)(best[n] & 0xFFFFFFFFull) & (NE - 1);
}

// K3: gather codebook rows, transpose-write z_q_st, loss partials, histogram, idx out.
__global__ __launch_bounds__(256) void gather_kernel(const float* __restrict__ z,
                                                     const float* __restrict__ w,
                                                     const unsigned* __restrict__ idxarr,
                                                     unsigned* __restrict__ counts,
                                                     float* __restrict__ loss,
                                                     float* __restrict__ out,
                                                     float* __restrict__ out_idx) {
    __shared__ int idx_s[64];
    __shared__ float wl[64 * 257];
    int tid = threadIdx.x;
    int n0 = blockIdx.x * 64;
    if (tid < 64) {
        int idx = (int)(idxarr[n0 + tid] & (NE - 1));
        idx_s[tid] = idx;
        out_idx[n0 + tid] = (float)idx;
        atomicAdd(&counts[idx], 1u);
    }
    __syncthreads();
    for (int i = 0; i < 64; ++i)
        wl[i * 257 + tid] = w[(size_t)idx_s[i] * EDIM + tid];
    __syncthreads();
    int tn = tid & 63, tc = tid >> 6;
    int bb_ = n0 >> 12, lhw0 = n0 & 4095;
    size_t zb = (size_t)bb_ * (EDIM * LHW) + lhw0 + tn;
    float accl = 0.f;
    for (int cc = 0; cc < 64; ++cc) {
        int c = tc * 64 + cc;
        float wv = wl[tn * 257 + c];
        size_t a = zb + (size_t)c * LHW;
        float zv = z[a];
        float diff = wv - zv;            // z_q - zc
        out[a] = zv + diff;              // replicate zc + (z_q - zc) rounding
        accl += diff * diff;
    }
    #pragma unroll
    for (int off = 32; off; off >>= 1) accl += __shfl_xor(accl, off, 64);
    if ((tid & 63) == 0) atomicAdd(loss, accl);
}

// K4: scalars
__global__ __launch_bounds__(256) void finalize_kernel(const unsigned* __restrict__ counts,
                                                       const float* __restrict__ loss,
                                                       float* __restrict__ out_scalars) {
    __shared__ float ss[4];
    __shared__ int uu[4];
    int tid = threadIdx.x;
    float s = 0.f;
    int uniq = 0;
    for (int i = tid; i < NE; i += 256) {
        unsigned c = counts[i];
        if (c > 0) {
            float p = (float)c * (1.0f / (float)NQ);
            s += p * logf(p + 1e-10f);
            uniq++;
        }
    }
    #pragma unroll
    for (int off = 32; off; off >>= 1) {
        s += __shfl_xor(s, off, 64);
        uniq += __shfl_xor(uniq, off, 64);
    }
    int wave = tid >> 6;
    if ((tid & 63) == 0) { ss[wave] = s; uu[wave] = uniq; }
    __syncthreads();
    if (tid == 0) {
        float st = ss[0] + ss[1] + ss[2] + ss[3];
        int ut = uu[0] + uu[1] + uu[2] + uu[3];
        out_scalars[0] = BETA * loss[0] * (1.0f / (float)(NQ * EDIM));  // loss
        out_scalars[1] = expf(-st);                                     // perplexity
        out_scalars[2] = (float)ut;                                     // unique
    }
}

extern "C" void kernel_launch(void* const* d_in, const int* in_sizes, int n_in,
                              void* d_out, int out_size, void* d_ws, size_t ws_size,
                              hipStream_t stream) {
    const float* z = (const float*)d_in[0];
    const float* w = (const float*)d_in[1];
    float* out = (float*)d_out;
    char* ws = (char*)d_ws;
    float* wsq = (float*)(ws + WS_WSQ);
    unsigned* counts = (unsigned*)(ws + WS_CNT);
    float* loss = (float*)(ws + WS_LOSS);
    unsigned* idxarr = (unsigned*)(ws + WS_IDX);
    unsigned long long* best = (unsigned long long*)(ws + WS_BEST);
    unsigned long long* best2 = (unsigned long long*)(ws + WS_BEST2);
    unsigned* Ap = (unsigned*)(ws + WS_APACK);
    unsigned* Bp = (unsigned*)(ws + WS_BPACK);

    int idx_off = out_size - NQ;
    int scal_off = idx_off - 3;
    float* out_idx = out + idx_off;
    float* out_scalars = out + scal_off;

    // z_q region of d_out doubles as the per-slice top-2 scratch (u32 keys,
    // written by dist_mfma, read by merge_kernel, overwritten by gather).
    unsigned* s1 = (unsigned*)out;

    hipMemsetAsync(counts, 0, NE * sizeof(unsigned), stream);
    hipMemsetAsync(loss, 0, sizeof(float), stream);

    wsq_kernel<<<NE / 4, 256, 0, stream>>>(w, wsq);

    if (ws_size >= (size_t)WS_NEED) {
        pack_z<<<NQ / 64, 256, 0, stream>>>(z, Ap);
        pack_w<<<NE / 16, 256, 0, stream>>>(w, Bp);
        dist_mfma<<<dim3(64, 128), 256, 0, stream>>>((const unsigned short*)Ap,
                                                     (const unsigned short*)Bp, wsq, s1);
        merge_kernel<<<NQ / 256, 256, 0, stream>>>(s1, best2);
        refine_kernel<<<NQ / 4, 256, 0, stream>>>(z, w, wsq, best2, idxarr);
    } else {
        hipMemsetAsync(best, 0xFF, NQ * sizeof(unsigned long long), stream);
        dist_fp32<<<dim3(4, 128), 256, 0, stream>>>(z, w, wsq, best);
        extract_idx<<<NQ / 256, 256, 0, stream>>>(best, idxarr);
    }

    gather_kernel<<<NQ / 64, 256, 0, stream>>>(z, w, idxarr, counts, loss, out, out_idx);
    finalize_kernel<<<1, 256, 0, stream>>>(counts, loss, out_scalars);
}

// Round 11
// 340.897 us; speedup vs baseline: 1.1953x; 1.0044x over previous
//
#include <hip/hip_runtime.h>

// Problem constants
#define NQ     16384       // 4*16*16*16 query vectors
#define EDIM   256
#define NE     8192
#define LHW    4096        // 16*16*16
#define BETA   0.25f

// ws layout (bytes)
#define WS_WSQ    0            // f32[NE]             32768
#define WS_CNT    32768        // u32[NE]             32768
#define WS_LOSS   65536        // f32 (+pad)          256
#define WS_IDX    65792        // u32[NQ]             65536
#define WS_BEST   131328       // u64[NQ] (fallback)  131072
#define WS_BEST2  262400       // u64[8][NQ][2]       2097152 (unused now, kept for layout)
#define WS_APACK  2359552      // ushort[NQ*512]      16777216
#define WS_BPACK  19136768     // ushort[NE*512]      8388608
#define WS_NEED   27525376

typedef __attribute__((ext_vector_type(8))) short bf16x8;
typedef __attribute__((ext_vector_type(4))) float f32x4;

__device__ __forceinline__ unsigned f32_sortable(float f) {
    unsigned b = __float_as_uint(f);
    return b ^ ((unsigned)((int)b >> 31) | 0x80000000u);   // 3 VALU ops
}
__device__ __forceinline__ unsigned short bf16_rn(float f) {
    unsigned u = __float_as_uint(f);
    return (unsigned short)((u + 0x7FFFu + ((u >> 16) & 1u)) >> 16);
}
__device__ __forceinline__ float bf16_tof(unsigned short h) {
    return __uint_as_float(((unsigned)h) << 16);
}

// K1a (MFMA path): wsq[e] = sum_d w[e][d]^2 (f64 accumulate) FUSED with
// pack_w (codebook -> Bp bf16 hi/lo row-major [e][512]). One wave per row.
__global__ __launch_bounds__(256) void wsq_pack_w(const float* __restrict__ w,
                                                  float* __restrict__ wsq,
                                                  unsigned* __restrict__ Bp32) {
    int wave = threadIdx.x >> 6, lane = threadIdx.x & 63;
    int row = blockIdx.x * 4 + wave;
    float4 v = *(const float4*)(w + (size_t)row * EDIM + lane * 4);
    double s = (double)v.x * v.x + (double)v.y * v.y +
               (double)v.z * v.z + (double)v.w * v.w;
    // pack the 4 elements this lane owns
    unsigned pk[4];
    float vv[4] = {v.x, v.y, v.z, v.w};
    #pragma unroll
    for (int t = 0; t < 4; ++t) {
        unsigned short hi = bf16_rn(vv[t]);
        unsigned short lo = bf16_rn(vv[t] - bf16_tof(hi));
        pk[t] = (unsigned)hi | ((unsigned)lo << 16);
    }
    *(uint4*)(Bp32 + (size_t)row * 256 + lane * 4) = make_uint4(pk[0], pk[1], pk[2], pk[3]);
    #pragma unroll
    for (int off = 32; off; off >>= 1) s += __shfl_xor(s, off, 64);
    if (lane == 0) wsq[row] = (float)s;
}

// K1b (fallback path): wsq only.
__global__ __launch_bounds__(256) void wsq_kernel(const float* __restrict__ w,
                                                  float* __restrict__ wsq) {
    int wave = threadIdx.x >> 6, lane = threadIdx.x & 63;
    int row = blockIdx.x * 4 + wave;
    float4 v = *(const float4*)(w + (size_t)row * EDIM + lane * 4);
    double s = (double)v.x * v.x + (double)v.y * v.y +
               (double)v.z * v.z + (double)v.w * v.w;
    #pragma unroll
    for (int off = 32; off; off >>= 1) s += __shfl_xor(s, off, 64);
    if (lane == 0) wsq[row] = (float)s;
}

// pack_z: z fp32 [4][256][4096] -> Ap bf16 hi/lo ROW-MAJOR [n][512].
__global__ __launch_bounds__(256) void pack_z(const float* __restrict__ z,
                                              unsigned* __restrict__ Ap32) {
    __shared__ unsigned lds[64 * 257];
    int tid = threadIdx.x;
    int tn = tid & 63, tc = tid >> 6;
    int n0 = blockIdx.x * 64;
    int n = n0 + tn;
    int b = n >> 12, lhw = n & 4095;
    for (int cc = 0; cc < 64; ++cc) {
        int d = tc * 64 + cc;
        float v = z[((size_t)b * EDIM + d) * LHW + lhw];
        unsigned short hi = bf16_rn(v);
        unsigned short lo = bf16_rn(v - bf16_tof(hi));
        lds[tn * 257 + d] = (unsigned)hi | ((unsigned)lo << 16);
    }
    __syncthreads();
    for (int p = 0; p < 64; ++p) {
        int flat = p * 256 + tid;
        int row = flat >> 8, cl = flat & 255;
        Ap32[(size_t)(n0 + row) * 256 + cl] = lds[row * 257 + cl];
    }
}

// K2-MFMA v8: round-10 structure with BK=128 (4 barrier-pairs instead of 8;
// 64 MFMA/wave between vmcnt(0) drains). LDS 32 KB single buffer (5 blocks/CU
// by LDS — avoids m132's 64KB occupancy cliff). Same XOR swizzle (0 conflicts
// measured in r8/r10). u32 epilogue keys unchanged (r10-verified).
__global__ __launch_bounds__(256, 2) void dist_mfma(const unsigned short* __restrict__ Ap,
                                                    const unsigned short* __restrict__ Bp,
                                                    const float* __restrict__ wsq,
                                                    unsigned* __restrict__ s1) {
    __shared__ __align__(16) unsigned short lds_b[128 * 128];   // 32 KB: row=128 shorts
    int tid = threadIdx.x, lane = tid & 63, w = tid >> 6;
    int x = blockIdx.x, nt = blockIdx.y;
    int quad = lane >> 4, col = lane & 15;
    int rsel = lane >> 4, seg = lane & 15;   // glds: 4 rows x 16 segs of 16B per call

    const unsigned short* arow = Ap + (size_t)(nt * 128 + w * 32 + col) * 512;
    const unsigned short* Bbase = Bp + (size_t)(x * 128) * 512;

    f32x4 acc[2][8];
    #pragma unroll
    for (int i = 0; i < 2; ++i)
        #pragma unroll
        for (int j = 0; j < 8; ++j) acc[i][j] = (f32x4){0.f, 0.f, 0.f, 0.f};

    for (int kcc = 0; kcc < 4; ++kcc) {
        int k0 = kcc * 128;
        // A frags for this 128k chunk: global -> VGPR (L2-resident tile)
        bf16x8 af[2][4];
        #pragma unroll
        for (int i = 0; i < 2; ++i)
            #pragma unroll
            for (int h = 0; h < 4; ++h)
                af[i][h] = *(const bf16x8*)(arow + i * 16 * 512 + k0 + h * 32 + quad * 8);
        __syncthreads();   // previous chunk's LDS readers done
        // stage B chunk: 32 calls of 1KB (8/wave). Row r -> LDS r*128 shorts;
        // slot s holds k-position s ^ (r&7) (reader xors the same way).
        #pragma unroll
        for (int p = 0; p < 8; ++p) {
            int c = w * 8 + p;
            int row = c * 4 + rsel;
            const unsigned short* gb =
                Bbase + (size_t)row * 512 + k0 + ((seg ^ (row & 7)) * 8);
            __builtin_amdgcn_global_load_lds(
                (const __attribute__((address_space(1))) void*)gb,
                (__attribute__((address_space(3))) void*)(lds_b + c * 512),
                16, 0, 0);
        }
        __syncthreads();   // drains vmcnt (glds + A loads) — 4x per kernel now
        #pragma unroll
        for (int h = 0; h < 4; ++h) {
            bf16x8 bf[8];
            #pragma unroll
            for (int j = 0; j < 8; ++j)
                bf[j] = *(const bf16x8*)(lds_b + (j * 16 + col) * 128 +
                                         (((h * 4 + quad) ^ (col & 7)) * 8));
            #pragma unroll
            for (int i = 0; i < 2; ++i)
                #pragma unroll
                for (int j = 0; j < 8; ++j)
                    acc[i][j] = __builtin_amdgcn_mfma_f32_16x16x32_bf16(
                        af[i][h], bf[j], acc[i][j], 0, 0, 0);
        }
    }

    // epilogue: d = wsq[e] - 2*dot; u32 key = trunc-sortable(d) | e_local;
    // branchless top-2 per (i,r), then cross-lane merge over 16 e-lanes.
    unsigned m1[2][4], m2[2][4];
    #pragma unroll
    for (int i = 0; i < 2; ++i)
        #pragma unroll
        for (int r = 0; r < 4; ++r) { m1[i][r] = 0xFFFFFFFFu; m2[i][r] = 0xFFFFFFFFu; }
    #pragma unroll
    for (int j = 0; j < 8; ++j) {
        int e = x * 128 + j * 16 + col;
        unsigned jc = (unsigned)(j * 16 + col);   // e_local, 7 bits
        float wq = wsq[e];
        #pragma unroll
        for (int i = 0; i < 2; ++i)
            #pragma unroll
            for (int r = 0; r < 4; ++r) {
                float d = fmaf(-2.0f, acc[i][j][r], wq);
                unsigned k = (f32_sortable(d) & 0xFFFFFF80u) | jc;
                unsigned mx = (m1[i][r] > k) ? m1[i][r] : k;
                m1[i][r] = (m1[i][r] < k) ? m1[i][r] : k;
                m2[i][r] = (m2[i][r] < mx) ? m2[i][r] : mx;
            }
    }
    #pragma unroll
    for (int i = 0; i < 2; ++i)
        #pragma unroll
        for (int r = 0; r < 4; ++r) {
            unsigned a1 = m1[i][r], a2 = m2[i][r];
            #pragma unroll
            for (int off = 1; off < 16; off <<= 1) {
                unsigned b1 = __shfl_xor(a1, off, 64);
                unsigned b2 = __shfl_xor(a2, off, 64);
                unsigned lo1 = a1 < b1 ? a1 : b1;
                unsigned hi1 = a1 < b1 ? b1 : a1;
                unsigned lo2 = a2 < b2 ? a2 : b2;
                a1 = lo1;
                a2 = hi1 < lo2 ? hi1 : lo2;
            }
            if (col == 0) {
                int q = nt * 128 + w * 32 + i * 16 + quad * 4 + r;
                size_t o = (size_t)q * 128 + x * 2;
                s1[o] = a1; s1[o + 1] = a2;
            }
        }
}

// Refine v2 (merge fused): per query, lane=slice holds its top-2 u32 keys;
// 3-step shfl-xor top-2 reduce within 8-lane groups -> 16 candidates
// (= top-2 per 1024-e-group, identical to the old merge+refine); then exact
// fp32 distance for all 16, true argmin with first-index tiebreak.
__global__ __launch_bounds__(256) void refine_kernel(const float* __restrict__ z,
                                                     const float* __restrict__ w,
                                                     const float* __restrict__ wsq,
                                                     const unsigned* __restrict__ s1,
                                                     unsigned* __restrict__ idxarr) {
    int tid = threadIdx.x, lane = tid & 63, wv = tid >> 6;
    int q = blockIdx.x * 4 + wv;
    int b = q >> 12, lhw = q & 4095;
    // slice keys -> global u64 keys: (d_trunc << 13) | e_global
    uint2 kk2 = *(const uint2*)(s1 + (size_t)q * 128 + lane * 2);
    unsigned long long a1 =
        ((unsigned long long)(kk2.x >> 7) << 13) | (unsigned)(lane * 128 + (kk2.x & 127u));
    unsigned long long a2 =
        ((unsigned long long)(kk2.y >> 7) << 13) | (unsigned)(lane * 128 + (kk2.y & 127u));
    #pragma unroll
    for (int off = 1; off < 8; off <<= 1) {
        unsigned long long b1 = __shfl_xor(a1, off, 64);
        unsigned long long b2 = __shfl_xor(a2, off, 64);
        unsigned long long lo1 = a1 < b1 ? a1 : b1;
        unsigned long long hi1 = a1 < b1 ? b1 : a1;
        unsigned long long lo2 = a2 < b2 ? a2 : b2;
        a1 = lo1;
        a2 = hi1 < lo2 ? hi1 : lo2;
    }
    float zv[4];
    #pragma unroll
    for (int t = 0; t < 4; ++t)
        zv[t] = z[((size_t)b * EDIM + lane * 4 + t) * LHW + lhw];
    unsigned long long bestk = ~0ull;
    #pragma unroll
    for (int c = 0; c < 16; ++c) {
        int src = (c >> 1) * 8;
        unsigned long long kc = (c & 1) ? __shfl(a2, src, 64) : __shfl(a1, src, 64);
        unsigned e = (unsigned)(kc & (unsigned long long)(NE - 1));
        float4 wv4 = *(const float4*)(w + (size_t)e * EDIM + lane * 4);
        float p = zv[0] * wv4.x + zv[1] * wv4.y + zv[2] * wv4.z + zv[3] * wv4.w;
        #pragma unroll
        for (int off = 32; off; off >>= 1) p += __shfl_xor(p, off, 64);
        float d = wsq[e] - 2.0f * p;
        unsigned long long key = ((unsigned long long)f32_sortable(d) << 32) | e;
        if (key < bestk) bestk = key;
    }
    if (lane == 0) idxarr[q] = (unsigned)(bestk & 0xFFFFFFFFull);
}

// ---------- fallback fp32 path (used when ws_size < WS_NEED) ----------
__global__ __launch_bounds__(256, 2) void dist_fp32(const float* __restrict__ z,
                                                    const float* __restrict__ w,
                                                    const float* __restrict__ wsq,
                                                    unsigned long long* __restrict__ best) {
    __shared__ float lds_a[32 * 128];
    __shared__ float lds_b[32 * 132];
    int tid = threadIdx.x;
    int tx = tid & 15, ty = tid >> 4;
    int n0 = blockIdx.y * 128;
    int bb_ = n0 >> 12, lhw0 = n0 & 4095;
    const float* zb = z + (size_t)bb_ * (EDIM * LHW) + lhw0;
    int ebase = blockIdx.x * 2048;
    unsigned long long runmin[8];
    #pragma unroll
    for (int i = 0; i < 8; ++i) runmin[i] = ~0ull;
    float acc[64];
    for (int et = 0; et < 16; ++et) {
        int e0 = ebase + et * 128;
        #pragma unroll
        for (int i = 0; i < 64; ++i) acc[i] = 0.f;
        for (int kc = 0; kc < 8; ++kc) {
            int k0 = kc * 32;
            #pragma unroll
            for (int p = 0; p < 4; ++p) {
                int f = p * 256 + tid;
                int kk = f >> 5, nn4 = f & 31;
                float4 v = *(const float4*)(zb + (size_t)(k0 + kk) * LHW + nn4 * 4);
                *((float4*)(lds_a + kk * 128 + nn4 * 4)) = v;
            }
            #pragma unroll
            for (int p = 0; p < 4; ++p) {
                int f = p * 256 + tid;
                int ee = f >> 3, kk4 = f & 7;
                float4 v = *(const float4*)(w + (size_t)(e0 + ee) * EDIM + k0 + kk4 * 4);
                lds_b[(kk4 * 4 + 0) * 132 + ee] = v.x;
                lds_b[(kk4 * 4 + 1) * 132 + ee] = v.y;
                lds_b[(kk4 * 4 + 2) * 132 + ee] = v.z;
                lds_b[(kk4 * 4 + 3) * 132 + ee] = v.w;
            }
            __syncthreads();
            #pragma unroll
            for (int k = 0; k < 32; ++k) {
                float a[8], bv[8];
                *(float4*)(a)      = *(float4*)(lds_a + k * 128 + ty * 8);
                *(float4*)(a + 4)  = *(float4*)(lds_a + k * 128 + ty * 8 + 4);
                *(float4*)(bv)     = *(float4*)(lds_b + k * 132 + tx * 8);
                *(float4*)(bv + 4) = *(float4*)(lds_b + k * 132 + tx * 8 + 4);
                #pragma unroll
                for (int i = 0; i < 8; ++i)
                    #pragma unroll
                    for (int j = 0; j < 8; ++j)
                        acc[i * 8 + j] = fmaf(a[i], bv[j], acc[i * 8 + j]);
            }
            __syncthreads();
        }
        #pragma unroll
        for (int i = 0; i < 8; ++i) {
            unsigned long long m = runmin[i];
            #pragma unroll
            for (int j = 0; j < 8; ++j) {
                int e = e0 + tx * 8 + j;
                float d = wsq[e] - 2.0f * acc[i * 8 + j];
                unsigned long long key =
                    ((unsigned long long)f32_sortable(d) << 32) | (unsigned)e;
                m = (m < key) ? m : key;
            }
            runmin[i] = m;
        }
    }
    #pragma unroll
    for (int i = 0; i < 8; ++i) {
        unsigned long long kk = runmin[i];
        #pragma unroll
        for (int off = 8; off >= 1; off >>= 1) {
            unsigned long long o = __shfl_xor(kk, off, 16);
            kk = (kk < o) ? kk : o;
        }
        if (tx == 0) atomicMin(&best[n0 + ty * 8 + i], kk);
    }
}

__global__ __launch_bounds__(256) void extract_idx(const unsigned long long* __restrict__ best,
                                                   unsigned* __restrict__ idxarr) {
    int n = blockIdx.x * 256 + threadIdx.x;
    idxarr[n] = (unsigned)(best[n] & 0xFFFFFFFFull) & (NE - 1);
}

// K3: gather codebook rows, transpose-write z_q_st, loss partials, histogram, idx out.
__global__ __launch_bounds__(256) void gather_kernel(const float* __restrict__ z,
                                                     const float* __restrict__ w,
                                                     const unsigned* __restrict__ idxarr,
                                                     unsigned* __restrict__ counts,
                                                     float* __restrict__ loss,
                                                     float* __restrict__ out,
                                                     float* __restrict__ out_idx) {
    __shared__ int idx_s[64];
    __shared__ float wl[64 * 257];
    int tid = threadIdx.x;
    int n0 = blockIdx.x * 64;
    if (tid < 64) {
        int idx = (int)(idxarr[n0 + tid] & (NE - 1));
        idx_s[tid] = idx;
        out_idx[n0 + tid] = (float)idx;
        atomicAdd(&counts[idx], 1u);
    }
    __syncthreads();
    for (int i = 0; i < 64; ++i)
        wl[i * 257 + tid] = w[(size_t)idx_s[i] * EDIM + tid];
    __syncthreads();
    int tn = tid & 63, tc = tid >> 6;
    int bb_ = n0 >> 12, lhw0 = n0 & 4095;
    size_t zb = (size_t)bb_ * (EDIM * LHW) + lhw0 + tn;
    float accl = 0.f;
    for (int cc = 0; cc < 64; ++cc) {
        int c = tc * 64 + cc;
        float wv = wl[tn * 257 + c];
        size_t a = zb + (size_t)c * LHW;
        float zv = z[a];
        float diff = wv - zv;            // z_q - zc
        out[a] = zv + diff;              // replicate zc + (z_q - zc) rounding
        accl += diff * diff;
    }
    #pragma unroll
    for (int off = 32; off; off >>= 1) accl += __shfl_xor(accl, off, 64);
    if ((tid & 63) == 0) atomicAdd(loss, accl);
}

// K4: scalars
__global__ __launch_bounds__(256) void finalize_kernel(const unsigned* __restrict__ counts,
                                                       const float* __restrict__ loss,
                                                       float* __restrict__ out_scalars) {
    __shared__ float ss[4];
    __shared__ int uu[4];
    int tid = threadIdx.x;
    float s = 0.f;
    int uniq = 0;
    for (int i = tid; i < NE; i += 256) {
        unsigned c = counts[i];
        if (c > 0) {
            float p = (float)c * (1.0f / (float)NQ);
            s += p * logf(p + 1e-10f);
            uniq++;
        }
    }
    #pragma unroll
    for (int off = 32; off; off >>= 1) {
        s += __shfl_xor(s, off, 64);
        uniq += __shfl_xor(uniq, off, 64);
    }
    int wave = tid >> 6;
    if ((tid & 63) == 0) { ss[wave] = s; uu[wave] = uniq; }
    __syncthreads();
    if (tid == 0) {
        float st = ss[0] + ss[1] + ss[2] + ss[3];
        int ut = uu[0] + uu[1] + uu[2] + uu[3];
        out_scalars[0] = BETA * loss[0] * (1.0f / (float)(NQ * EDIM));  // loss
        out_scalars[1] = expf(-st);                                     // perplexity
        out_scalars[2] = (float)ut;                                     // unique
    }
}

extern "C" void kernel_launch(void* const* d_in, const int* in_sizes, int n_in,
                              void* d_out, int out_size, void* d_ws, size_t ws_size,
                              hipStream_t stream) {
    const float* z = (const float*)d_in[0];
    const float* w = (const float*)d_in[1];
    float* out = (float*)d_out;
    char* ws = (char*)d_ws;
    float* wsq = (float*)(ws + WS_WSQ);
    unsigned* counts = (unsigned*)(ws + WS_CNT);
    float* loss = (float*)(ws + WS_LOSS);
    unsigned* idxarr = (unsigned*)(ws + WS_IDX);
    unsigned long long* best = (unsigned long long*)(ws + WS_BEST);
    unsigned* Ap = (unsigned*)(ws + WS_APACK);
    unsigned* Bp = (unsigned*)(ws + WS_BPACK);

    int idx_off = out_size - NQ;
    int scal_off = idx_off - 3;
    float* out_idx = out + idx_off;
    float* out_scalars = out + scal_off;

    // z_q region of d_out doubles as the per-slice top-2 scratch (u32 keys,
    // written by dist_mfma, read by refine, overwritten by gather).
    unsigned* s1 = (unsigned*)out;

    hipMemsetAsync(counts, 0, NE * sizeof(unsigned), stream);
    hipMemsetAsync(loss, 0, sizeof(float), stream);

    if (ws_size >= (size_t)WS_NEED) {
        wsq_pack_w<<<NE / 4, 256, 0, stream>>>(w, wsq, Bp);
        pack_z<<<NQ / 64, 256, 0, stream>>>(z, Ap);
        dist_mfma<<<dim3(64, 128), 256, 0, stream>>>((const unsigned short*)Ap,
                                                     (const unsigned short*)Bp, wsq, s1);
        refine_kernel<<<NQ / 4, 256, 0, stream>>>(z, w, wsq, s1, idxarr);
    } else {
        wsq_kernel<<<NE / 4, 256, 0, stream>>>(w, wsq);
        hipMemsetAsync(best, 0xFF, NQ * sizeof(unsigned long long), stream);
        dist_fp32<<<dim3(4, 128), 256, 0, stream>>>(z, w, wsq, best);
        extract_idx<<<NQ / 256, 256, 0, stream>>>(best, idxarr);
    }

    gather_kernel<<<NQ / 64, 256, 0, stream>>>(z, w, idxarr, counts, loss, out, out_idx);
    finalize_kernel<<<1, 256, 0, stream>>>(counts, loss, out_scalars);
}

// Round 12
// 340.831 us; speedup vs baseline: 1.1956x; 1.0002x over previous
//
#include <hip/hip_runtime.h>

// Problem constants
#define NQ     16384       // 4*16*16*16 query vectors
#define EDIM   256
#define NE     8192
#define LHW    4096        // 16*16*16
#define BETA   0.25f

// ws layout (bytes)
#define WS_WSQ    0            // f32[NE]             32768
#define WS_CNT    32768        // u32[NE]             32768
#define WS_LOSS   65536        // f32 (+pad)          256
#define WS_IDX    65792        // u32[NQ]             65536
#define WS_BEST   131328       // u64[NQ] (fallback)  131072
#define WS_APACK  2359552      // ushort[NQ*512]      16777216
#define WS_BPACK  19136768     // ushort[NE*512]      8388608
#define WS_NEED   27525376

typedef __attribute__((ext_vector_type(8))) short bf16x8;
typedef __attribute__((ext_vector_type(4))) float f32x4;

__device__ __forceinline__ unsigned f32_sortable(float f) {
    unsigned b = __float_as_uint(f);
    return b ^ ((unsigned)((int)b >> 31) | 0x80000000u);   // 3 VALU ops
}
__device__ __forceinline__ unsigned short bf16_rn(float f) {
    unsigned u = __float_as_uint(f);
    return (unsigned short)((u + 0x7FFFu + ((u >> 16) & 1u)) >> 16);
}
__device__ __forceinline__ float bf16_tof(unsigned short h) {
    return __uint_as_float(((unsigned)h) << 16);
}

// K1a (MFMA path): wsq + pack_w fused; also zeroes counts/loss (saves 2 memsets).
__global__ __launch_bounds__(256) void wsq_pack_w(const float* __restrict__ w,
                                                  float* __restrict__ wsq,
                                                  unsigned* __restrict__ Bp32,
                                                  unsigned* __restrict__ counts,
                                                  float* __restrict__ loss) {
    int wave = threadIdx.x >> 6, lane = threadIdx.x & 63;
    int row = blockIdx.x * 4 + wave;
    if (blockIdx.x < 32) {
        counts[blockIdx.x * 256 + threadIdx.x] = 0u;
        if (blockIdx.x == 0 && threadIdx.x == 0) loss[0] = 0.f;
    }
    float4 v = *(const float4*)(w + (size_t)row * EDIM + lane * 4);
    double s = (double)v.x * v.x + (double)v.y * v.y +
               (double)v.z * v.z + (double)v.w * v.w;
    unsigned pk[4];
    float vv[4] = {v.x, v.y, v.z, v.w};
    #pragma unroll
    for (int t = 0; t < 4; ++t) {
        unsigned short hi = bf16_rn(vv[t]);
        unsigned short lo = bf16_rn(vv[t] - bf16_tof(hi));
        pk[t] = (unsigned)hi | ((unsigned)lo << 16);
    }
    *(uint4*)(Bp32 + (size_t)row * 256 + lane * 4) = make_uint4(pk[0], pk[1], pk[2], pk[3]);
    #pragma unroll
    for (int off = 32; off; off >>= 1) s += __shfl_xor(s, off, 64);
    if (lane == 0) wsq[row] = (float)s;
}

// K1b (fallback path): wsq only.
__global__ __launch_bounds__(256) void wsq_kernel(const float* __restrict__ w,
                                                  float* __restrict__ wsq) {
    int wave = threadIdx.x >> 6, lane = threadIdx.x & 63;
    int row = blockIdx.x * 4 + wave;
    float4 v = *(const float4*)(w + (size_t)row * EDIM + lane * 4);
    double s = (double)v.x * v.x + (double)v.y * v.y +
               (double)v.z * v.z + (double)v.w * v.w;
    #pragma unroll
    for (int off = 32; off; off >>= 1) s += __shfl_xor(s, off, 64);
    if (lane == 0) wsq[row] = (float)s;
}

// pack_z: z fp32 [4][256][4096] -> Ap bf16 hi/lo ROW-MAJOR [n][512].
__global__ __launch_bounds__(256) void pack_z(const float* __restrict__ z,
                                              unsigned* __restrict__ Ap32) {
    __shared__ unsigned lds[64 * 257];
    int tid = threadIdx.x;
    int tn = tid & 63, tc = tid >> 6;
    int n0 = blockIdx.x * 64;
    int n = n0 + tn;
    int b = n >> 12, lhw = n & 4095;
    for (int cc = 0; cc < 64; ++cc) {
        int d = tc * 64 + cc;
        float v = z[((size_t)b * EDIM + d) * LHW + lhw];
        unsigned short hi = bf16_rn(v);
        unsigned short lo = bf16_rn(v - bf16_tof(hi));
        lds[tn * 257 + d] = (unsigned)hi | ((unsigned)lo << 16);
    }
    __syncthreads();
    for (int p = 0; p < 64; ++p) {
        int flat = p * 256 + tid;
        int row = flat >> 8, cl = flat & 255;
        Ap32[(size_t)(n0 + row) * 256 + cl] = lds[row * 257 + cl];
    }
}

// K2-MFMA v9: r10's verified BK=64 loop (0 conflicts) with wave tile 64n x 128e
// (i=4): each B-fragment LDS read now feeds 4 MFMAs, halving the LDS-port
// floor (82 -> 41 µs), which r11 showed to be the largest co-limiter.
// Block = 4 waves stacked on n -> 256n x 128e; grid (64 e-splits, 64 nt).
// A: direct global->VGPR. B: glds-staged 16KB/chunk, r10 XOR swizzle.
// Regs: acc 128 + af 32 + bf 32 + keys 32 (epilogue) + addr ~20 -> peak ~212.
__global__ __launch_bounds__(256, 2) void dist_mfma(const unsigned short* __restrict__ Ap,
                                                    const unsigned short* __restrict__ Bp,
                                                    const float* __restrict__ wsq,
                                                    unsigned* __restrict__ s1) {
    __shared__ __align__(16) unsigned short lds_b[128 * 64];   // 16 KB, swizzled
    int tid = threadIdx.x, lane = tid & 63, w = tid >> 6;
    int x = blockIdx.x, nt = blockIdx.y;
    int quad = lane >> 4, col = lane & 15;
    int rsel = lane >> 3, seg = lane & 7;   // glds: 8 rows x 8 segs of 16B per call

    const unsigned short* arow = Ap + (size_t)(nt * 256 + w * 64 + col) * 512;
    const unsigned short* Bbase = Bp + (size_t)(x * 128) * 512;

    f32x4 acc[4][8];
    #pragma unroll
    for (int i = 0; i < 4; ++i)
        #pragma unroll
        for (int j = 0; j < 8; ++j) acc[i][j] = (f32x4){0.f, 0.f, 0.f, 0.f};

    for (int kcc = 0; kcc < 8; ++kcc) {
        int k0 = kcc * 64;
        // A frags for this 64k chunk: global -> VGPR (L2-resident tile)
        bf16x8 af[4][2];
        #pragma unroll
        for (int i = 0; i < 4; ++i)
            #pragma unroll
            for (int h = 0; h < 2; ++h)
                af[i][h] = *(const bf16x8*)(arow + i * 16 * 512 + k0 + h * 32 + quad * 8);
        __syncthreads();   // previous chunk's LDS readers done
        // stage B chunk: 16 calls of 1KB (4/wave), r10 swizzle (0 conflicts).
        #pragma unroll
        for (int p = 0; p < 4; ++p) {
            int c = w * 4 + p;
            const unsigned short* gb =
                Bbase + (size_t)(c * 8 + rsel) * 512 + k0 + ((seg ^ (rsel & 7)) * 8);
            __builtin_amdgcn_global_load_lds(
                (const __attribute__((address_space(1))) void*)gb,
                (__attribute__((address_space(3))) void*)(lds_b + c * 512),
                16, 0, 0);
        }
        __syncthreads();   // drains vmcnt (glds + A loads)
        #pragma unroll
        for (int h = 0; h < 2; ++h) {
            bf16x8 bf[8];
            #pragma unroll
            for (int j = 0; j < 8; ++j)
                bf[j] = *(const bf16x8*)(lds_b + (j * 16 + col) * 64 +
                                         (((h * 4 + quad) ^ (col & 7)) * 8));
            #pragma unroll
            for (int i = 0; i < 4; ++i)
                #pragma unroll
                for (int j = 0; j < 8; ++j)
                    acc[i][j] = __builtin_amdgcn_mfma_f32_16x16x32_bf16(
                        af[i][h], bf[j], acc[i][j], 0, 0, 0);
        }
    }

    // epilogue: d = wsq[e] - 2*dot; u32 key = trunc-sortable(d) | e_local;
    // branchless top-2 per (i,r), then cross-lane merge over 16 e-lanes.
    unsigned m1[4][4], m2[4][4];
    #pragma unroll
    for (int i = 0; i < 4; ++i)
        #pragma unroll
        for (int r = 0; r < 4; ++r) { m1[i][r] = 0xFFFFFFFFu; m2[i][r] = 0xFFFFFFFFu; }
    #pragma unroll
    for (int j = 0; j < 8; ++j) {
        int e = x * 128 + j * 16 + col;
        unsigned jc = (unsigned)(j * 16 + col);   // e_local, 7 bits
        float wq = wsq[e];
        #pragma unroll
        for (int i = 0; i < 4; ++i)
            #pragma unroll
            for (int r = 0; r < 4; ++r) {
                float d = fmaf(-2.0f, acc[i][j][r], wq);
                unsigned k = (f32_sortable(d) & 0xFFFFFF80u) | jc;
                unsigned mx = (m1[i][r] > k) ? m1[i][r] : k;
                m1[i][r] = (m1[i][r] < k) ? m1[i][r] : k;
                m2[i][r] = (m2[i][r] < mx) ? m2[i][r] : mx;
            }
    }
    #pragma unroll
    for (int i = 0; i < 4; ++i)
        #pragma unroll
        for (int r = 0; r < 4; ++r) {
            unsigned a1 = m1[i][r], a2 = m2[i][r];
            #pragma unroll
            for (int off = 1; off < 16; off <<= 1) {
                unsigned b1 = __shfl_xor(a1, off, 64);
                unsigned b2 = __shfl_xor(a2, off, 64);
                unsigned lo1 = a1 < b1 ? a1 : b1;
                unsigned hi1 = a1 < b1 ? b1 : a1;
                unsigned lo2 = a2 < b2 ? a2 : b2;
                a1 = lo1;
                a2 = hi1 < lo2 ? hi1 : lo2;
            }
            if (col == 0) {
                int q = nt * 256 + w * 64 + i * 16 + quad * 4 + r;
                size_t o = (size_t)q * 128 + x * 2;
                s1[o] = a1; s1[o + 1] = a2;
            }
        }
}

// Refine (merge fused): per query, lane=slice holds its top-2 u32 keys;
// 3-step shfl-xor top-2 reduce within 8-lane groups -> 16 candidates
// (top-2 per 1024-e group); then exact fp32 distance for all 16,
// true argmin with first-index tiebreak. One wave per query.
__global__ __launch_bounds__(256) void refine_kernel(const float* __restrict__ z,
                                                     const float* __restrict__ w,
                                                     const float* __restrict__ wsq,
                                                     const unsigned* __restrict__ s1,
                                                     unsigned* __restrict__ idxarr) {
    int tid = threadIdx.x, lane = tid & 63, wv = tid >> 6;
    int q = blockIdx.x * 4 + wv;
    int b = q >> 12, lhw = q & 4095;
    // slice keys -> global u64 keys: (d_trunc << 13) | e_global
    uint2 kk2 = *(const uint2*)(s1 + (size_t)q * 128 + lane * 2);
    unsigned long long a1 =
        ((unsigned long long)(kk2.x >> 7) << 13) | (unsigned)(lane * 128 + (kk2.x & 127u));
    unsigned long long a2 =
        ((unsigned long long)(kk2.y >> 7) << 13) | (unsigned)(lane * 128 + (kk2.y & 127u));
    #pragma unroll
    for (int off = 1; off < 8; off <<= 1) {
        unsigned long long b1 = __shfl_xor(a1, off, 64);
        unsigned long long b2 = __shfl_xor(a2, off, 64);
        unsigned long long lo1 = a1 < b1 ? a1 : b1;
        unsigned long long hi1 = a1 < b1 ? b1 : a1;
        unsigned long long lo2 = a2 < b2 ? a2 : b2;
        a1 = lo1;
        a2 = hi1 < lo2 ? hi1 : lo2;
    }
    float zv[4];
    #pragma unroll
    for (int t = 0; t < 4; ++t)
        zv[t] = z[((size_t)b * EDIM + lane * 4 + t) * LHW + lhw];
    unsigned long long bestk = ~0ull;
    #pragma unroll
    for (int c = 0; c < 16; ++c) {
        int src = (c >> 1) * 8;
        unsigned long long kc = (c & 1) ? __shfl(a2, src, 64) : __shfl(a1, src, 64);
        unsigned e = (unsigned)(kc & (unsigned long long)(NE - 1));
        float4 wv4 = *(const float4*)(w + (size_t)e * EDIM + lane * 4);
        float p = zv[0] * wv4.x + zv[1] * wv4.y + zv[2] * wv4.z + zv[3] * wv4.w;
        #pragma unroll
        for (int off = 32; off; off >>= 1) p += __shfl_xor(p, off, 64);
        float d = wsq[e] - 2.0f * p;
        unsigned long long key = ((unsigned long long)f32_sortable(d) << 32) | e;
        if (key < bestk) bestk = key;
    }
    if (lane == 0) idxarr[q] = (unsigned)(bestk & 0xFFFFFFFFull);
}

// ---------- fallback fp32 path (used when ws_size < WS_NEED) ----------
__global__ __launch_bounds__(256, 2) void dist_fp32(const float* __restrict__ z,
                                                    const float* __restrict__ w,
                                                    const float* __restrict__ wsq,
                                                    unsigned long long* __restrict__ best) {
    __shared__ float lds_a[32 * 128];
    __shared__ float lds_b[32 * 132];
    int tid = threadIdx.x;
    int tx = tid & 15, ty = tid >> 4;
    int n0 = blockIdx.y * 128;
    int bb_ = n0 >> 12, lhw0 = n0 & 4095;
    const float* zb = z + (size_t)bb_ * (EDIM * LHW) + lhw0;
    int ebase = blockIdx.x * 2048;
    unsigned long long runmin[8];
    #pragma unroll
    for (int i = 0; i < 8; ++i) runmin[i] = ~0ull;
    float acc[64];
    for (int et = 0; et < 16; ++et) {
        int e0 = ebase + et * 128;
        #pragma unroll
        for (int i = 0; i < 64; ++i) acc[i] = 0.f;
        for (int kc = 0; kc < 8; ++kc) {
            int k0 = kc * 32;
            #pragma unroll
            for (int p = 0; p < 4; ++p) {
                int f = p * 256 + tid;
                int kk = f >> 5, nn4 = f & 31;
                float4 v = *(const float4*)(zb + (size_t)(k0 + kk) * LHW + nn4 * 4);
                *((float4*)(lds_a + kk * 128 + nn4 * 4)) = v;
            }
            #pragma unroll
            for (int p = 0; p < 4; ++p) {
                int f = p * 256 + tid;
                int ee = f >> 3, kk4 = f & 7;
                float4 v = *(const float4*)(w + (size_t)(e0 + ee) * EDIM + k0 + kk4 * 4);
                lds_b[(kk4 * 4 + 0) * 132 + ee] = v.x;
                lds_b[(kk4 * 4 + 1) * 132 + ee] = v.y;
                lds_b[(kk4 * 4 + 2) * 132 + ee] = v.z;
                lds_b[(kk4 * 4 + 3) * 132 + ee] = v.w;
            }
            __syncthreads();
            #pragma unroll
            for (int k = 0; k < 32; ++k) {
                float a[8], bv[8];
                *(float4*)(a)      = *(float4*)(lds_a + k * 128 + ty * 8);
                *(float4*)(a + 4)  = *(float4*)(lds_a + k * 128 + ty * 8 + 4);
                *(float4*)(bv)     = *(float4*)(lds_b + k * 132 + tx * 8);
                *(float4*)(bv + 4) = *(float4*)(lds_b + k * 132 + tx * 8 + 4);
                #pragma unroll
                for (int i = 0; i < 8; ++i)
                    #pragma unroll
                    for (int j = 0; j < 8; ++j)
                        acc[i * 8 + j] = fmaf(a[i], bv[j], acc[i * 8 + j]);
            }
            __syncthreads();
        }
        #pragma unroll
        for (int i = 0; i < 8; ++i) {
            unsigned long long m = runmin[i];
            #pragma unroll
            for (int j = 0; j < 8; ++j) {
                int e = e0 + tx * 8 + j;
                float d = wsq[e] - 2.0f * acc[i * 8 + j];
                unsigned long long key =
                    ((unsigned long long)f32_sortable(d) << 32) | (unsigned)e;
                m = (m < key) ? m : key;
            }
            runmin[i] = m;
        }
    }
    #pragma unroll
    for (int i = 0; i < 8; ++i) {
        unsigned long long kk = runmin[i];
        #pragma unroll
        for (int off = 8; off >= 1; off >>= 1) {
            unsigned long long o = __shfl_xor(kk, off, 16);
            kk = (kk < o) ? kk : o;
        }
        if (tx == 0) atomicMin(&best[n0 + ty * 8 + i], kk);
    }
}

__global__ __launch_bounds__(256) void extract_idx(const unsigned long long* __restrict__ best,
                                                   unsigned* __restrict__ idxarr) {
    int n = blockIdx.x * 256 + threadIdx.x;
    idxarr[n] = (unsigned)(best[n] & 0xFFFFFFFFull) & (NE - 1);
}

// K3: gather codebook rows, transpose-write z_q_st, loss partials, histogram, idx out.
__global__ __launch_bounds__(256) void gather_kernel(const float* __restrict__ z,
                                                     const float* __restrict__ w,
                                                     const unsigned* __restrict__ idxarr,
                                                     unsigned* __restrict__ counts,
                                                     float* __restrict__ loss,
                                                     float* __restrict__ out,
                                                     float* __restrict__ out_idx) {
    __shared__ int idx_s[64];
    __shared__ float wl[64 * 257];
    int tid = threadIdx.x;
    int n0 = blockIdx.x * 64;
    if (tid < 64) {
        int idx = (int)(idxarr[n0 + tid] & (NE - 1));
        idx_s[tid] = idx;
        out_idx[n0 + tid] = (float)idx;
        atomicAdd(&counts[idx], 1u);
    }
    __syncthreads();
    for (int i = 0; i < 64; ++i)
        wl[i * 257 + tid] = w[(size_t)idx_s[i] * EDIM + tid];
    __syncthreads();
    int tn = tid & 63, tc = tid >> 6;
    int bb_ = n0 >> 12, lhw0 = n0 & 4095;
    size_t zb = (size_t)bb_ * (EDIM * LHW) + lhw0 + tn;
    float accl = 0.f;
    for (int cc = 0; cc < 64; ++cc) {
        int c = tc * 64 + cc;
        float wv = wl[tn * 257 + c];
        size_t a = zb + (size_t)c * LHW;
        float zv = z[a];
        float diff = wv - zv;            // z_q - zc
        out[a] = zv + diff;              // replicate zc + (z_q - zc) rounding
        accl += diff * diff;
    }
    #pragma unroll
    for (int off = 32; off; off >>= 1) accl += __shfl_xor(accl, off, 64);
    if ((tid & 63) == 0) atomicAdd(loss, accl);
}

// K4: scalars
__global__ __launch_bounds__(256) void finalize_kernel(const unsigned* __restrict__ counts,
                                                       const float* __restrict__ loss,
                                                       float* __restrict__ out_scalars) {
    __shared__ float ss[4];
    __shared__ int uu[4];
    int tid = threadIdx.x;
    float s = 0.f;
    int uniq = 0;
    for (int i = tid; i < NE; i += 256) {
        unsigned c = counts[i];
        if (c > 0) {
            float p = (float)c * (1.0f / (float)NQ);
            s += p * logf(p + 1e-10f);
            uniq++;
        }
    }
    #pragma unroll
    for (int off = 32; off; off >>= 1) {
        s += __shfl_xor(s, off, 64);
        uniq += __shfl_xor(uniq, off, 64);
    }
    int wave = tid >> 6;
    if ((tid & 63) == 0) { ss[wave] = s; uu[wave] = uniq; }
    __syncthreads();
    if (tid == 0) {
        float st = ss[0] + ss[1] + ss[2] + ss[3];
        int ut = uu[0] + uu[1] + uu[2] + uu[3];
        out_scalars[0] = BETA * loss[0] * (1.0f / (float)(NQ * EDIM));  // loss
        out_scalars[1] = expf(-st);                                     // perplexity
        out_scalars[2] = (float)ut;                                     // unique
    }
}

extern "C" void kernel_launch(void* const* d_in, const int* in_sizes, int n_in,
                              void* d_out, int out_size, void* d_ws, size_t ws_size,
                              hipStream_t stream) {
    const float* z = (const float*)d_in[0];
    const float* w = (const float*)d_in[1];
    float* out = (float*)d_out;
    char* ws = (char*)d_ws;
    float* wsq = (float*)(ws + WS_WSQ);
    unsigned* counts = (unsigned*)(ws + WS_CNT);
    float* loss = (float*)(ws + WS_LOSS);
    unsigned* idxarr = (unsigned*)(ws + WS_IDX);
    unsigned long long* best = (unsigned long long*)(ws + WS_BEST);
    unsigned* Ap = (unsigned*)(ws + WS_APACK);
    unsigned* Bp = (unsigned*)(ws + WS_BPACK);

    int idx_off = out_size - NQ;
    int scal_off = idx_off - 3;
    float* out_idx = out + idx_off;
    float* out_scalars = out + scal_off;

    // z_q region of d_out doubles as the per-slice top-2 scratch (u32 keys,
    // written by dist_mfma, read by refine, overwritten by gather).
    unsigned* s1 = (unsigned*)out;

    if (ws_size >= (size_t)WS_NEED) {
        wsq_pack_w<<<NE / 4, 256, 0, stream>>>(w, wsq, Bp, counts, loss);
        pack_z<<<NQ / 64, 256, 0, stream>>>(z, Ap);
        dist_mfma<<<dim3(64, 64), 256, 0, stream>>>((const unsigned short*)Ap,
                                                    (const unsigned short*)Bp, wsq, s1);
        refine_kernel<<<NQ / 4, 256, 0, stream>>>(z, w, wsq, s1, idxarr);
    } else {
        hipMemsetAsync(counts, 0, NE * sizeof(unsigned), stream);
        hipMemsetAsync(loss, 0, sizeof(float), stream);
        wsq_kernel<<<NE / 4, 256, 0, stream>>>(w, wsq);
        hipMemsetAsync(best, 0xFF, NQ * sizeof(unsigned long long), stream);
        dist_fp32<<<dim3(4, 128), 256, 0, stream>>>(z, w, wsq, best);
        extract_idx<<<NQ / 256, 256, 0, stream>>>(best, idxarr);
    }

    gather_kernel<<<NQ / 64, 256, 0, stream>>>(z, w, idxarr, counts, loss, out, out_idx);
    finalize_kernel<<<1, 256, 0, stream>>>(counts, loss, out_scalars);
}